// Round 5
// baseline (259.175 us; speedup 1.0000x reference)
//
#include <hip/hip_runtime.h>

#define NN 50000
#define NE 800000
#define ND 64
#define ED 32
#define HID 64
#define NL 2
#define IN_MSG 96   // ND + ED
#define IN_UPD 128  // ND + HID

#define W1_LD 104   // ushort stride for W1^T rows (96+8), 208B = 16B-aligned
#define H_LD 72     // ushort stride for h rows (64+8), 144B = 16B-aligned
#define UPD_LD 136  // ushort stride for node comb rows (128+8)

#define NBLK 768            // 3 blocks/CU x 256 CUs
#define WPB 4
#define TOTW (NBLK * WPB)   // 3072 waves
#define NGRP (NE / 32)      // 25000 groups of 32 edges

typedef __attribute__((ext_vector_type(8))) short short8;  // 8 bf16 = 4 VGPR
typedef __attribute__((ext_vector_type(4))) float f32x4;

__device__ inline ushort bf16r(float f) {  // fp32 -> bf16, RNE
    union { float f; unsigned u; } x; x.f = f;
    return (ushort)((x.u + 0x7FFFu + ((x.u >> 16) & 1u)) >> 16);
}
__device__ inline short8 pk8(float4 a, float4 b) {
    short8 r;
    r[0] = (short)bf16r(a.x); r[1] = (short)bf16r(a.y);
    r[2] = (short)bf16r(a.z); r[3] = (short)bf16r(a.w);
    r[4] = (short)bf16r(b.x); r[5] = (short)bf16r(b.y);
    r[6] = (short)bf16r(b.z); r[7] = (short)bf16r(b.w);
    return r;
}
__device__ inline uint2 pack4(float4 v) {
    return make_uint2((unsigned)bf16r(v.x) | ((unsigned)bf16r(v.y) << 16),
                      (unsigned)bf16r(v.z) | ((unsigned)bf16r(v.w) << 16));
}

// ---------------------------------------------------------------------------
// Edge message MLP: persistent barrier-free waves, 3 blocks/CU.
// A-fragments loaded DIRECTLY from global (lane reads its own 8-float slices)
// and packed to bf16 in-register -> no combined-feature LDS at all.
// Per wave-group: 32 edges x 64 outputs. W1^T/W2^T in LDS (staged once),
// h transposed through a 16-row wave-private LDS buffer (mt-split).
// idx prefetched 2 generations ahead; ef/nf one generation ahead.
// ---------------------------------------------------------------------------
__global__ __launch_bounds__(256, 3)
void edge_msg_kernel(const float* __restrict__ nf,
                     const float* __restrict__ ef,
                     const float* __restrict__ w1,
                     const float* __restrict__ b1,
                     const float* __restrict__ w2,
                     const float* __restrict__ b2,
                     const int* __restrict__ src,
                     const int* __restrict__ dst,
                     float* __restrict__ agg,
                     float* __restrict__ deg)
{
    __shared__ __align__(16) ushort sW1t[NL][64][W1_LD];  // 26,624 B
    __shared__ __align__(16) ushort sW2t[NL][64][64];     // 16,384 B (XOR-swizzled)
    __shared__ __align__(16) ushort sH[WPB][16][H_LD];    //  9,216 B  => 52,224 B total

    const int tid = threadIdx.x;
    const int w  = tid >> 6;
    const int l  = tid & 63;
    const int lr = l & 15;
    const int lg = l >> 4;

    // ---- one-time stage: W1^T (padded) + W2^T (XOR-swizzled chunks) ----
    {
        const int k16 = tid >> 4, n0 = (tid & 15) * 4;
        #pragma unroll
        for (int lay = 0; lay < NL; ++lay) {
            #pragma unroll
            for (int it = 0; it < 6; ++it) {
                const int k = k16 + 16 * it;   // 0..95
                const float4 v = *reinterpret_cast<const float4*>(
                    w1 + ((size_t)lay * IN_MSG + k) * HID + n0);
                sW1t[lay][n0 + 0][k] = bf16r(v.x);
                sW1t[lay][n0 + 1][k] = bf16r(v.y);
                sW1t[lay][n0 + 2][k] = bf16r(v.z);
                sW1t[lay][n0 + 3][k] = bf16r(v.w);
            }
            #pragma unroll
            for (int it = 0; it < 4; ++it) {
                const int k = k16 + 16 * it;   // 0..63
                const float4 v = *reinterpret_cast<const float4*>(
                    w2 + ((size_t)lay * HID + k) * HID + n0);
                const ushort vals[4] = {bf16r(v.x), bf16r(v.y), bf16r(v.z), bf16r(v.w)};
                #pragma unroll
                for (int j = 0; j < 4; ++j) {
                    const int row = n0 + j;
                    const int colS = (((k >> 3) ^ (row & 7)) << 3) | (k & 7);
                    sW2t[lay][row][colS] = vals[j];
                }
            }
        }
    }
    // ---- biases in registers (per-lane constants) ----
    float bias1[NL][4], bias2s[4];
    #pragma unroll
    for (int lay = 0; lay < NL; ++lay)
        #pragma unroll
        for (int nt = 0; nt < 4; ++nt)
            bias1[lay][nt] = b1[lay * HID + nt * 16 + lr];
    #pragma unroll
    for (int nt = 0; nt < 4; ++nt)
        bias2s[nt] = b2[nt * 16 + lr] + b2[HID + nt * 16 + lr];
    __syncthreads();   // weights visible; the only block-wide barrier

    const float4* nfr = reinterpret_cast<const float4*>(nf);  // 16 float4 / row
    const float4* efr = reinterpret_cast<const float4*>(ef);  //  8 float4 / row

    // ---- prologue for first group ----
    int g = blockIdx.x * WPB + w;
    int srcv = 0, dstv = 0, srcn = 0, dstn = 0;
    if (l < 32) { srcv = src[(size_t)g * 32 + l]; dstv = dst[(size_t)g * 32 + l]; }
    {
        const int gn = g + TOTW;
        if (gn < NGRP && l < 32) { srcn = src[(size_t)gn * 32 + l]; dstn = dst[(size_t)gn * 32 + l]; }
    }
    float4 nfv[2][4], efv[2][2];
    #pragma unroll
    for (int mt = 0; mt < 2; ++mt) {
        const int s = __shfl(srcv, mt * 16 + lr);
        const float4* p = nfr + (size_t)s * 16;
        nfv[mt][0] = p[2 * lg];     nfv[mt][1] = p[2 * lg + 1];
        nfv[mt][2] = p[8 + 2 * lg]; nfv[mt][3] = p[9 + 2 * lg];
        const float4* q = efr + (size_t)(g * 32 + mt * 16 + lr) * 8;
        efv[mt][0] = q[2 * lg];     efv[mt][1] = q[2 * lg + 1];
    }

    #pragma unroll 1
    while (g < NGRP) {
        const int gn  = g + TOTW;
        const int gnn = g + 2 * TOTW;
        const bool more = (gn < NGRP);

        // pack current group's A-fragments (waits on last iteration's loads)
        short8 cmbA[2][3];
        #pragma unroll
        for (int mt = 0; mt < 2; ++mt) {
            cmbA[mt][0] = pk8(nfv[mt][0], nfv[mt][1]);
            cmbA[mt][1] = pk8(nfv[mt][2], nfv[mt][3]);
            cmbA[mt][2] = pk8(efv[mt][0], efv[mt][1]);
        }

        // prefetch idx two generations ahead
        int srcn2 = 0, dstn2 = 0;
        if (gnn < NGRP && l < 32) {
            srcn2 = src[(size_t)gnn * 32 + l];
            dstn2 = dst[(size_t)gnn * 32 + l];
        }
        // prefetch next group's edge features (streamed; longest latency)
        float4 nfn[2][4], efn[2][2];
        if (more) {
            #pragma unroll
            for (int mt = 0; mt < 2; ++mt) {
                const float4* q = efr + (size_t)(gn * 32 + mt * 16 + lr) * 8;
                efn[mt][0] = q[2 * lg]; efn[mt][1] = q[2 * lg + 1];
            }
        }

        f32x4 msg[2][4];
        #pragma unroll
        for (int nt = 0; nt < 4; ++nt) {
            const float v = bias2s[nt];
            msg[0][nt] = (f32x4){v, v, v, v};
            msg[1][nt] = (f32x4){v, v, v, v};
        }

        #pragma unroll
        for (int lay = 0; lay < NL; ++lay) {
            #pragma unroll
            for (int mt = 0; mt < 2; ++mt) {
                // ---- GEMM1(mt): h = relu(cmb @ W1 + b1), K=96 ----
                f32x4 acc[4];
                #pragma unroll
                for (int nt = 0; nt < 4; ++nt) {
                    const float bv = bias1[lay][nt];
                    acc[nt] = (f32x4){bv, bv, bv, bv};
                }
                __builtin_amdgcn_s_setprio(1);
                #pragma unroll
                for (int ks = 0; ks < 3; ++ks)
                    #pragma unroll
                    for (int nt = 0; nt < 4; ++nt) {
                        const short8 B = *reinterpret_cast<const short8*>(
                            &sW1t[lay][nt * 16 + lr][ks * 32 + 8 * lg]);
                        acc[nt] = __builtin_amdgcn_mfma_f32_16x16x32_bf16(
                            cmbA[mt][ks], B, acc[nt], 0, 0, 0);
                    }
                __builtin_amdgcn_s_setprio(0);
                // write h (C layout: col=lane&15, row=(lane>>4)*4+reg)
                #pragma unroll
                for (int nt = 0; nt < 4; ++nt)
                    #pragma unroll
                    for (int r = 0; r < 4; ++r)
                        sH[w][4 * lg + r][nt * 16 + lr] = bf16r(fmaxf(acc[nt][r], 0.0f));
                // read h A-frags (in-wave DS ordering makes this safe)
                const short8 h0 = *reinterpret_cast<const short8*>(&sH[w][lr][ 0 + 8 * lg]);
                const short8 h1 = *reinterpret_cast<const short8*>(&sH[w][lr][32 + 8 * lg]);
                // ---- GEMM2(mt): msg += h @ W2, K=64 (swizzled B reads) ----
                __builtin_amdgcn_s_setprio(1);
                #pragma unroll
                for (int nt = 0; nt < 4; ++nt) {
                    const int cB = nt * 16 + lr;
                    const short8 B0 = *reinterpret_cast<const short8*>(
                        &sW2t[lay][cB][((0 + lg) ^ (lr & 7)) << 3]);
                    const short8 B1 = *reinterpret_cast<const short8*>(
                        &sW2t[lay][cB][((4 + lg) ^ (lr & 7)) << 3]);
                    msg[mt][nt] = __builtin_amdgcn_mfma_f32_16x16x32_bf16(h0, B0, msg[mt][nt], 0, 0, 0);
                    msg[mt][nt] = __builtin_amdgcn_mfma_f32_16x16x32_bf16(h1, B1, msg[mt][nt], 0, 0, 0);
                }
                __builtin_amdgcn_s_setprio(0);
            }
            // after layer 0: issue next group's node gathers (hide under layer 1)
            if (lay == 0 && more) {
                #pragma unroll
                for (int mt = 0; mt < 2; ++mt) {
                    const int s = __shfl(srcn, mt * 16 + lr);
                    const float4* p = nfr + (size_t)s * 16;
                    nfn[mt][0] = p[2 * lg];     nfn[mt][1] = p[2 * lg + 1];
                    nfn[mt][2] = p[8 + 2 * lg]; nfn[mt][3] = p[9 + 2 * lg];
                }
            }
        }

        // ---- flush: direct C-frag atomics (4 rows x 64B contiguous / instr) ----
        #pragma unroll
        for (int mt = 0; mt < 2; ++mt)
            #pragma unroll
            for (int r = 0; r < 4; ++r) {
                const int drow = __shfl(dstv, mt * 16 + 4 * lg + r);
                float* rowp = agg + (size_t)drow * HID;
                #pragma unroll
                for (int nt = 0; nt < 4; ++nt)
                    atomicAdd(rowp + nt * 16 + lr, msg[mt][nt][r]);
            }
        if (l < 32) atomicAdd(&deg[dstv], 1.0f);

        // rotate pipeline state
        srcv = srcn; dstv = dstn; srcn = srcn2; dstn = dstn2;
        #pragma unroll
        for (int mt = 0; mt < 2; ++mt) {
            #pragma unroll
            for (int i = 0; i < 4; ++i) nfv[mt][i] = nfn[mt][i];
            efv[mt][0] = efn[mt][0]; efv[mt][1] = efn[mt][1];
        }
        g = gn;
    }
}

// ---------------------------------------------------------------------------
// Node update MLP via bf16 MFMA (unchanged from round 4: validated, small).
// ---------------------------------------------------------------------------
__global__ __launch_bounds__(256, 2)
void node_update_kernel(const float* __restrict__ nf,
                        const float* __restrict__ agg,
                        const float* __restrict__ deg,
                        const float* __restrict__ uw1,
                        const float* __restrict__ ub1,
                        const float* __restrict__ uw2,
                        const float* __restrict__ ub2,
                        float* __restrict__ out)
{
    __shared__ __align__(16) ushort sAct[WPB][32][UPD_LD];
    __shared__ __align__(16) ushort sW1t[64][UPD_LD];
    __shared__ __align__(16) ushort sW2t[64][H_LD];
    __shared__ float sUB1[64], sUB2[64];

    const int tid = threadIdx.x;
    const int w  = tid >> 6;
    const int l  = tid & 63;
    const int lr = l & 15;
    const int lg = l >> 4;

    {   // weight stage
        const int k16 = tid >> 4, n0 = (tid & 15) * 4;
        #pragma unroll
        for (int it = 0; it < 8; ++it) {
            const int k = k16 + 16 * it;    // 0..127
            const float4 v = *reinterpret_cast<const float4*>(uw1 + (size_t)k * HID + n0);
            sW1t[n0 + 0][k] = bf16r(v.x);
            sW1t[n0 + 1][k] = bf16r(v.y);
            sW1t[n0 + 2][k] = bf16r(v.z);
            sW1t[n0 + 3][k] = bf16r(v.w);
        }
        #pragma unroll
        for (int it = 0; it < 4; ++it) {
            const int k = k16 + 16 * it;    // 0..63
            const float4 v = *reinterpret_cast<const float4*>(uw2 + (size_t)k * ND + n0);
            sW2t[n0 + 0][k] = bf16r(v.x);
            sW2t[n0 + 1][k] = bf16r(v.y);
            sW2t[n0 + 2][k] = bf16r(v.z);
            sW2t[n0 + 3][k] = bf16r(v.w);
        }
        if (tid < 64) { sUB1[tid] = ub1[tid]; sUB2[tid] = ub2[tid]; }
    }

    const int nbase = blockIdx.x * 128 + w * 32;

    float invv = 0.0f;
    if (l < 32) invv = 1.0f / (deg[min(nbase + l, NN - 1)] + 1e-8f);

    #pragma unroll
    for (int it = 0; it < 8; ++it) {
        const int row = lg + 4 * it;
        const int n = min(nbase + row, NN - 1);
        const float4 v = reinterpret_cast<const float4*>(nf + (size_t)n * ND)[lr];
        *reinterpret_cast<uint2*>(&sAct[w][row][lr * 4]) = pack4(v);
    }
    #pragma unroll
    for (int it = 0; it < 8; ++it) {
        const int row = lg + 4 * it;
        const int n = min(nbase + row, NN - 1);
        const float iv = __shfl(invv, row);
        float4 v = reinterpret_cast<const float4*>(agg + (size_t)n * HID)[lr];
        v.x *= iv; v.y *= iv; v.z *= iv; v.w *= iv;
        *reinterpret_cast<uint2*>(&sAct[w][row][ND + lr * 4]) = pack4(v);
    }
    __syncthreads();

    short8 A[2][4];
    #pragma unroll
    for (int mt = 0; mt < 2; ++mt)
        #pragma unroll
        for (int ks = 0; ks < 4; ++ks)
            A[mt][ks] = *reinterpret_cast<const short8*>(&sAct[w][mt * 16 + lr][ks * 32 + 8 * lg]);
    #pragma unroll
    for (int nt = 0; nt < 4; ++nt) {
        const int cB = nt * 16 + lr;
        short8 B[4];
        #pragma unroll
        for (int ks = 0; ks < 4; ++ks)
            B[ks] = *reinterpret_cast<const short8*>(&sW1t[cB][ks * 32 + 8 * lg]);
        const float bv = sUB1[cB];
        #pragma unroll
        for (int mt = 0; mt < 2; ++mt) {
            f32x4 acc = (f32x4){bv, bv, bv, bv};
            #pragma unroll
            for (int ks = 0; ks < 4; ++ks)
                acc = __builtin_amdgcn_mfma_f32_16x16x32_bf16(A[mt][ks], B[ks], acc, 0, 0, 0);
            const int rH = mt * 16 + 4 * lg;
            #pragma unroll
            for (int r = 0; r < 4; ++r)
                sAct[w][rH + r][cB] = bf16r(fmaxf(acc[r], 0.0f));
        }
    }

    f32x4 o[2][4];
    #pragma unroll
    for (int nt = 0; nt < 4; ++nt) {
        const float v = sUB2[nt * 16 + lr];
        o[0][nt] = (f32x4){v, v, v, v};
        o[1][nt] = (f32x4){v, v, v, v};
    }
    #pragma unroll
    for (int mt = 0; mt < 2; ++mt) {
        const short8 A0 = *reinterpret_cast<const short8*>(&sAct[w][mt * 16 + lr][ 0 + 8 * lg]);
        const short8 A1 = *reinterpret_cast<const short8*>(&sAct[w][mt * 16 + lr][32 + 8 * lg]);
        #pragma unroll
        for (int nt = 0; nt < 4; ++nt) {
            const int cB = nt * 16 + lr;
            const short8 B0 = *reinterpret_cast<const short8*>(&sW2t[cB][ 0 + 8 * lg]);
            const short8 B1 = *reinterpret_cast<const short8*>(&sW2t[cB][32 + 8 * lg]);
            o[mt][nt] = __builtin_amdgcn_mfma_f32_16x16x32_bf16(A0, B0, o[mt][nt], 0, 0, 0);
            o[mt][nt] = __builtin_amdgcn_mfma_f32_16x16x32_bf16(A1, B1, o[mt][nt], 0, 0, 0);
        }
    }

    #pragma unroll
    for (int mt = 0; mt < 2; ++mt)
        #pragma unroll
        for (int r = 0; r < 4; ++r) {
            const int n = nbase + mt * 16 + 4 * lg + r;
            if (n < NN) {
                float* rowp = out + (size_t)n * ND;
                #pragma unroll
                for (int nt = 0; nt < 4; ++nt)
                    rowp[nt * 16 + lr] = o[mt][nt][r];
            }
        }
}

extern "C" void kernel_launch(void* const* d_in, const int* in_sizes, int n_in,
                              void* d_out, int out_size, void* d_ws, size_t ws_size,
                              hipStream_t stream)
{
    const float* nf  = (const float*)d_in[0];
    const float* ef  = (const float*)d_in[1];
    const float* w1  = (const float*)d_in[2];
    const float* b1  = (const float*)d_in[3];
    const float* w2  = (const float*)d_in[4];
    const float* b2  = (const float*)d_in[5];
    const float* uw1 = (const float*)d_in[6];
    const float* ub1 = (const float*)d_in[7];
    const float* uw2 = (const float*)d_in[8];
    const float* ub2 = (const float*)d_in[9];
    const int*   src = (const int*)d_in[10];
    const int*   dst = (const int*)d_in[11];
    float* out = (float*)d_out;

    float* agg = (float*)d_ws;                    // [NN][HID]
    float* deg = agg + (size_t)NN * HID;          // [NN]
    hipMemsetAsync(d_ws, 0, ((size_t)NN * HID + NN) * sizeof(float), stream);

    edge_msg_kernel<<<NBLK, 256, 0, stream>>>(nf, ef, w1, b1, w2, b2,
                                              src, dst, agg, deg);
    node_update_kernel<<<(NN + 127) / 128, 256, 0, stream>>>(nf, agg, deg,
                                                             uw1, ub1, uw2, ub2, out);
}